// Round 12
// baseline (217.813 us; speedup 1.0000x reference)
//
#include <hip/hip_runtime.h>

typedef float floatx4 __attribute__((ext_vector_type(4)));
typedef _Float16 half2v __attribute__((ext_vector_type(2)));
typedef _Float16 half8 __attribute__((ext_vector_type(8)));

#define Hh 128
#define Ww 256
#define Cc 64
#define COUT 64
#define Bb 4
#define HW (Hh*Ww)
#define VP 74

// Combined prep: bx<2 -> x NCHW fp32 -> NHWC fp16;
// bx==2 -> weight (o,c,kt) fp32 -> fp16 [kt][o][c].
__global__ void prep(const float* __restrict__ x, const float* __restrict__ wsrc,
                     _Float16* __restrict__ xn, unsigned short* __restrict__ wdst) {
    const int bx = blockIdx.x, h = blockIdx.y, b = blockIdx.z;
    const int tid = threadIdx.x;
    if (bx == 2) {
        const int i = (h + Hh * b) * 72 + tid;
        if (tid < 72) {
            const int kt = i % 9, c = (i / 9) % Cc, o = i / (9 * Cc);
            _Float16 hv = (_Float16)wsrc[i];
            wdst[(kt * COUT + o) * Cc + c] = *(unsigned short*)&hv;
        }
        return;
    }
    __shared__ unsigned short T[128][VP];
    const int wl = tid & 127;
    const int ch = tid >> 7;
    const float* sp = x + ((b * Cc + ch * 32) * Hh + h) * Ww + bx * 128 + wl;
#pragma unroll
    for (int c2 = 0; c2 < 16; ++c2) {
        const float v0 = sp[(2 * c2) * HW];
        const float v1 = sp[(2 * c2 + 1) * HW];
        half2v hv; hv.x = (_Float16)v0; hv.y = (_Float16)v1;
        *(unsigned*)&T[wl][ch * 32 + 2 * c2] = *(unsigned*)&hv;
    }
    __syncthreads();
    uint4* drow = (uint4*)(xn + ((size_t)(b * Hh + h) * Ww + bx * 128) * 64);
#pragma unroll
    for (int j = 0; j < 4; ++j) {
        const int idx = j * 256 + tid;
        drow[idx] = *(const uint4*)&T[idx >> 3][(idx & 7) * 8];
    }
}

struct TapS {
    half2v W00, W01, W10, W11;   // packed (w,w) fp16 corner weights
    int a00, a01, a10, a11;      // (y*Ww+x)*8 + kg  (uint4 units; +4*g per k-group)
};

__device__ __forceinline__ void tap_setup(int kt, int h, int w, float dy, float dx,
                                          int kg, TapS& t) {
    const int ki = kt / 3, kj = kt % 3;
    const float py = (float)(h - 1 + ki) + dy;
    const float px = (float)(w - 1 + kj) + dx;
    const float y0f = floorf(py), x0f = floorf(px);
    const int y0 = (int)y0f, x0 = (int)x0f;
    const float ly = py - y0f, lx = px - x0f;
    const int y1 = y0 + 1, x1 = x0 + 1;
    const bool vy0 = ((unsigned)y0 < Hh), vy1 = ((unsigned)y1 < Hh);
    const bool vx0 = ((unsigned)x0 < Ww), vx1 = ((unsigned)x1 < Ww);
    const float w00 = (vy0 && vx0) ? (1.f - ly) * (1.f - lx) : 0.f;
    const float w01 = (vy0 && vx1) ? (1.f - ly) * lx : 0.f;
    const float w10 = (vy1 && vx0) ? ly * (1.f - lx) : 0.f;
    const float w11 = (vy1 && vx1) ? ly * lx : 0.f;
    _Float16 h00 = (_Float16)w00, h01 = (_Float16)w01;
    _Float16 h10 = (_Float16)w10, h11 = (_Float16)w11;
    t.W00.x = h00; t.W00.y = h00;  t.W01.x = h01; t.W01.y = h01;
    t.W10.x = h10; t.W10.y = h10;  t.W11.x = h11; t.W11.y = h11;
    const int y0c = min(max(y0, 0), Hh - 1), y1c = min(max(y1, 0), Hh - 1);
    const int x0c = min(max(x0, 0), Ww - 1), x1c = min(max(x1, 0), Ww - 1);
    t.a00 = (y0c * Ww + x0c) * 8 + kg;
    t.a01 = (y0c * Ww + x1c) * 8 + kg;
    t.a10 = (y1c * Ww + x0c) * 8 + kg;
    t.a11 = (y1c * Ww + x1c) * 8 + kg;
}

// bilinear combine of 4 gathered corner fragments -> MFMA B-fragment (half8)
__device__ __forceinline__ half8 combine4(const TapS& t, const uint4 (&c)[4]) {
    union { unsigned u[4]; half8 h; } r;
    const half2v* p0 = (const half2v*)&c[0];
    const half2v* p1 = (const half2v*)&c[1];
    const half2v* p2 = (const half2v*)&c[2];
    const half2v* p3 = (const half2v*)&c[3];
#pragma unroll
    for (int s = 0; s < 4; ++s) {
        half2v v = p0[s] * t.W00 + p1[s] * t.W01 + p2[s] * t.W10 + p3[s] * t.W11;
        r.u[s] = *(unsigned*)&v;
    }
    return r.h;
}

// One pipeline stage S = (kt, g), S in [0,18). Issue order contract:
//   WF(S) -> [boundary: offsets / setup] -> corners(S+1) -> combine(S)
//   [waits corners(S), older than everything issued here] -> mfma(S)
//   [waits WF(S), leaves corners(S+1) in flight].  No barriers anywhere.
template<int S>
__device__ __forceinline__ void stage(
    const uint4* __restrict__ xb4, const float* __restrict__ offb,
    const unsigned short* __restrict__ wfb,
    int h, int w, int kg,
    TapS& t0, TapS& t1, uint4 (&cb)[2][4],
    float (&oy)[2], float (&ox)[2],
    floatx4 (&acc)[4])
{
    constexpr int KT = S >> 1, G = S & 1;
    TapS& tS = (KT & 1) ? t1 : t0;

    // 1. weight fragments for this stage (L1-hot: all waves read same 8KB/tap)
    half8 WF[4];
#pragma unroll
    for (int mi = 0; mi < 4; ++mi)
        WF[mi] = *(const half8*)(wfb + KT * COUT * Cc + mi * 16 * Cc + G * 32);

    // 2. boundary work + prefetch next stage's corners
    if constexpr (G == 0) {
        if constexpr (KT + 2 <= 8) {
            oy[KT & 1] = offb[(2 * (KT + 2)) * HW];
            ox[KT & 1] = offb[(2 * (KT + 2) + 1) * HW];
        }
        cb[1][0] = xb4[tS.a00 + 4]; cb[1][1] = xb4[tS.a01 + 4];
        cb[1][2] = xb4[tS.a10 + 4]; cb[1][3] = xb4[tS.a11 + 4];
    } else if constexpr (KT < 8) {
        TapS& tT = (KT & 1) ? t0 : t1;
        tap_setup(KT + 1, h, w, oy[(KT + 1) & 1], ox[(KT + 1) & 1], kg, tT);
        cb[0][0] = xb4[tT.a00]; cb[0][1] = xb4[tT.a01];
        cb[0][2] = xb4[tT.a10]; cb[0][3] = xb4[tT.a11];
    }

    // 3. combine current stage's corners -> B-fragment
    half8 bf = combine4(tS, cb[G]);

    // 4. MFMA: 4 m-tiles
#pragma unroll
    for (int mi = 0; mi < 4; ++mi)
        acc[mi] = __builtin_amdgcn_mfma_f32_16x16x32_f16(WF[mi], bf, acc[mi], 0, 0, 0);
}

// Barrier-free, LDS-free implicit GEMM. Each wave is fully independent:
// 16 positions x 64 Cout. Gather lands directly in B-fragment layout
// (lane ln: pos=ln&15, channels (ln>>4)*8..+8 per k-group). 2048 blocks.
__launch_bounds__(256, 4)
__global__ void dcn_mfma(const _Float16* __restrict__ xn,   // NHWC fp16
                         const float* __restrict__ offset,
                         const unsigned short* __restrict__ wb,
                         const float* __restrict__ bias,
                         float* __restrict__ out) {
    const int tid = threadIdx.x;
    const int ln  = tid & 63;
    const int wv  = tid >> 6;
    const int b   = blockIdx.z;
    const int h   = blockIdx.y;
    const int w0  = blockIdx.x * 64 + wv * 16;   // this wave's 16 positions
    const int pos = ln & 15;
    const int kg  = ln >> 4;
    const int w   = w0 + pos;

    const uint4* xb4  = (const uint4*)(xn + (size_t)b * HW * 64);
    const float* offb = offset + b * 18 * HW + h * Ww + w;
    const unsigned short* wfb = wb + pos * Cc + kg * 8;   // per-lane A-frag base

    floatx4 acc[4];
#pragma unroll
    for (int mi = 0; mi < 4; ++mi) acc[mi] = (floatx4)0.f;

    uint4 cb[2][4];
    TapS t0, t1;
    float oy[2], ox[2];

    // prologue: offsets taps 0,1; setup tap 0; corners (0, g0)
    oy[0] = offb[0];        ox[0] = offb[HW];
    oy[1] = offb[2 * HW];   ox[1] = offb[3 * HW];
    tap_setup(0, h, w, oy[0], ox[0], kg, t0);
    cb[0][0] = xb4[t0.a00]; cb[0][1] = xb4[t0.a01];
    cb[0][2] = xb4[t0.a10]; cb[0][3] = xb4[t0.a11];

#define ST(S) stage<S>(xb4, offb, wfb, h, w, kg, t0, t1, cb, oy, ox, acc)
    ST(0);  ST(1);  ST(2);  ST(3);  ST(4);  ST(5);
    ST(6);  ST(7);  ST(8);  ST(9);  ST(10); ST(11);
    ST(12); ST(13); ST(14); ST(15); ST(16); ST(17);
#undef ST

    // epilogue: C/D layout col=lane&15 (pos), row=(lane>>4)*4+reg (o)
    float* outp = out + b * COUT * HW + h * Ww + w0 + pos;
#pragma unroll
    for (int mi = 0; mi < 4; ++mi)
#pragma unroll
        for (int r = 0; r < 4; ++r) {
            const int o = mi * 16 + kg * 4 + r;
            outp[o * HW] = acc[mi][r] + bias[o];
        }
}

extern "C" void kernel_launch(void* const* d_in, const int* in_sizes, int n_in,
                              void* d_out, int out_size, void* d_ws, size_t ws_size,
                              hipStream_t stream) {
    const float* x      = (const float*)d_in[0];
    const float* offset = (const float*)d_in[1];
    const float* weight = (const float*)d_in[2];
    const float* bias   = (const float*)d_in[3];
    float* out = (float*)d_out;

    _Float16* xn = (_Float16*)d_ws;                          // 16.8 MiB NHWC fp16
    unsigned short* wb = (unsigned short*)((char*)d_ws + (size_t)Bb * HW * Cc * 2);

    prep<<<dim3(3, Hh, Bb), 256, 0, stream>>>(x, weight, xn, wb);
    dcn_mfma<<<dim3(Ww / 64, Hh, Bb), 256, 0, stream>>>(xn, offset, wb, bias, out);
}

// Round 13
// 176.696 us; speedup vs baseline: 1.2327x; 1.2327x over previous
//
#include <hip/hip_runtime.h>

typedef float floatx4 __attribute__((ext_vector_type(4)));
typedef _Float16 half2v __attribute__((ext_vector_type(2)));
typedef _Float16 half8 __attribute__((ext_vector_type(8)));

#define Hh 128
#define Ww 256
#define Cc 64
#define COUT 64
#define Bb 4
#define HW (Hh*Ww)
#define VP 74   // LDS V row stride in shorts: 37 dwords ≡ 5 (mod 32) -> <=2-way (free)

// prep: bx<4 -> x NCHW fp32 -> NHWC fp16, 64-w quarter per block (2048 blocks);
// bx==4 -> weight (o,c,kt) fp32 -> fp16 [kt][o][c].
__global__ void prep(const float* __restrict__ x, const float* __restrict__ wsrc,
                     _Float16* __restrict__ xn, unsigned short* __restrict__ wdst) {
    const int bx = blockIdx.x, h = blockIdx.y, b = blockIdx.z;
    const int tid = threadIdx.x;
    if (bx == 4) {
        const int i = (h + Hh * b) * 72 + tid;
        if (tid < 72) {
            const int kt = i % 9, c = (i / 9) % Cc, o = i / (9 * Cc);
            _Float16 hv = (_Float16)wsrc[i];
            wdst[(kt * COUT + o) * Cc + c] = *(unsigned short*)&hv;
        }
        return;
    }
    __shared__ unsigned short T[64][VP];
    const int wl  = tid & 63;           // position within quarter-row
    const int ch4 = tid >> 6;           // channel quarter (16 ch each)
    const float* sp = x + ((b * Cc + ch4 * 16) * Hh + h) * Ww + bx * 64 + wl;
#pragma unroll
    for (int c2 = 0; c2 < 8; ++c2) {
        const float v0 = sp[(2 * c2) * HW];
        const float v1 = sp[(2 * c2 + 1) * HW];
        half2v hv; hv.x = (_Float16)v0; hv.y = (_Float16)v1;
        *(unsigned*)&T[wl][ch4 * 16 + 2 * c2] = *(unsigned*)&hv;
    }
    __syncthreads();
    uint4* drow = (uint4*)(xn + ((size_t)(b * Hh + h) * Ww + bx * 64) * 64);  // 512 uint4
#pragma unroll
    for (int j = 0; j < 2; ++j) {
        const int idx = j * 256 + tid;
        drow[idx] = *(const uint4*)&T[idx >> 3][(idx & 7) * 8];
    }
}

// Raw barrier: lgkmcnt(0) only; in-flight global loads survive.
__device__ __forceinline__ void lds_barrier() {
    asm volatile("s_waitcnt lgkmcnt(0)\n\ts_barrier" ::: "memory");
}

struct Tap {
    half2v W00, W01, W10, W11;   // packed (w,w) fp16 corner weights
    int a00, a01, a10, a11;      // corner addresses in uint4 (16B) units
};

__device__ __forceinline__ void tap_setup(int kt, int h, int w, float dy, float dx,
                                          int cg, Tap& t) {
    const int ki = kt / 3, kj = kt % 3;
    const float py = (float)(h - 1 + ki) + dy;
    const float px = (float)(w - 1 + kj) + dx;
    const float y0f = floorf(py), x0f = floorf(px);
    const int y0 = (int)y0f, x0 = (int)x0f;
    const float ly = py - y0f, lx = px - x0f;
    const int y1 = y0 + 1, x1 = x0 + 1;
    const bool vy0 = ((unsigned)y0 < Hh), vy1 = ((unsigned)y1 < Hh);
    const bool vx0 = ((unsigned)x0 < Ww), vx1 = ((unsigned)x1 < Ww);
    const float w00 = (vy0 && vx0) ? (1.f - ly) * (1.f - lx) : 0.f;
    const float w01 = (vy0 && vx1) ? (1.f - ly) * lx : 0.f;
    const float w10 = (vy1 && vx0) ? ly * (1.f - lx) : 0.f;
    const float w11 = (vy1 && vx1) ? ly * lx : 0.f;
    _Float16 h00 = (_Float16)w00, h01 = (_Float16)w01;
    _Float16 h10 = (_Float16)w10, h11 = (_Float16)w11;
    t.W00.x = h00; t.W00.y = h00;  t.W01.x = h01; t.W01.y = h01;
    t.W10.x = h10; t.W10.y = h10;  t.W11.x = h11; t.W11.y = h11;
    const int y0c = min(max(y0, 0), Hh - 1), y1c = min(max(y1, 0), Hh - 1);
    const int x0c = min(max(x0, 0), Ww - 1), x1c = min(max(x1, 0), Ww - 1);
    t.a00 = (y0c * Ww + x0c) * 8 + cg;   // 8 uint4/pos; cg = 1 uint4 (8ch)
    t.a01 = (y0c * Ww + x1c) * 8 + cg;
    t.a10 = (y1c * Ww + x0c) * 8 + cg;
    t.a11 = (y1c * Ww + x1c) * 8 + cg;
}

__device__ __forceinline__ void tap_load(const uint4* __restrict__ xb4, const Tap& t,
                                         unsigned (&pf)[16]) {
    *(uint4*)&pf[0]  = xb4[t.a00];
    *(uint4*)&pf[4]  = xb4[t.a01];
    *(uint4*)&pf[8]  = xb4[t.a10];
    *(uint4*)&pf[12] = xb4[t.a11];
}

// weight a-fragments for one tap (this wave's 2 m-tiles x 2 k-groups)
__device__ __forceinline__ void wf_load(const unsigned short* __restrict__ wt,
                                        half8 (&WF)[4]) {
    WF[0] = *(const half8*)(wt);
    WF[1] = *(const half8*)(wt + 16 * Cc);
    WF[2] = *(const half8*)(wt + 32);
    WF[3] = *(const half8*)(wt + 16 * Cc + 32);
}

__device__ __forceinline__ void tap_store(const Tap& t, const unsigned (&pf)[16],
                                          unsigned short* __restrict__ vrow) {
    unsigned o[4];
#pragma unroll
    for (int s = 0; s < 4; ++s) {
        half2v v = (*(const half2v*)&pf[s])      * t.W00
                 + (*(const half2v*)&pf[4 + s])  * t.W01
                 + (*(const half2v*)&pf[8 + s])  * t.W10
                 + (*(const half2v*)&pf[12 + s]) * t.W11;
        o[s] = *(unsigned*)&v;
    }
    uint4 u; u.x = o[0]; u.y = o[1]; u.z = o[2]; u.w = o[3];
    *(uint4*)vrow = u;
}

__device__ __forceinline__ void mfma_tap(const half8 (&WF)[4],
                                         const unsigned short* __restrict__ Vbuf,
                                         int nt, int ln, floatx4 (&acc)[2]) {
#pragma unroll
    for (int g = 0; g < 2; ++g) {
        const int pp = nt * 16 + (ln & 15);
        half8 bfrag = *(const half8*)&Vbuf[pp * VP + g * 32 + (ln >> 4) * 8];
        acc[0] = __builtin_amdgcn_mfma_f32_16x16x32_f16(WF[2 * g],     bfrag, acc[0], 0, 0, 0);
        acc[1] = __builtin_amdgcn_mfma_f32_16x16x32_f16(WF[2 * g + 1], bfrag, acc[1], 0, 0, 0);
    }
}

template<int KT>
__device__ __forceinline__ void pipe_iter(
    const uint4* __restrict__ xb4, const float* __restrict__ offb,
    const unsigned short* __restrict__ wfb,
    const unsigned short* __restrict__ V0, const unsigned short* __restrict__ V1,
    unsigned short* __restrict__ vrow0, unsigned short* __restrict__ vrow1,
    int h, int w, int cg, int nt, int ln,
    Tap& tp0, Tap& tp1, unsigned (&pf0)[16], unsigned (&pf1)[16],
    half8 (&WF0)[4], half8 (&WF1)[4],
    float& dy0, float& dx0, float& dy1, float& dx1,
    floatx4 (&acc)[2])
{
    constexpr int S = KT & 1, T = 1 - S;
    wf_load(wfb + KT * COUT * Cc, S ? WF1 : WF0);
    if constexpr (KT < 8) {
        tap_setup(KT + 1, h, w, T ? dy1 : dy0, T ? dx1 : dx0, cg, T ? tp1 : tp0);
        tap_load(xb4, T ? tp1 : tp0, T ? pf1 : pf0);
    }
    if constexpr (KT + 3 <= 8) {
        (T ? dy1 : dy0) = offb[(2 * (KT + 3)) * HW];
        (T ? dx1 : dx0) = offb[(2 * (KT + 3) + 1) * HW];
    }
    mfma_tap(T ? WF1 : WF0, T ? V1 : V0, nt, ln, acc);
    tap_store(S ? tp1 : tp0, S ? pf1 : pf0, S ? vrow1 : vrow0);
    lds_barrier();
}

// R11 pipeline + XCD-aware slab swizzle: 1D grid 4096; blocks with bx%8==i
// (round-robin -> XCD i) cover contiguous 32-row slabs (2.1MB, fits 4MB L2)
// to kill cross-XCD L2 line replication of the 16.8MB xn working set.
__launch_bounds__(256, 4)
__global__ void dcn_mfma(const _Float16* __restrict__ xn,   // NHWC fp16
                         const float* __restrict__ offset,
                         const unsigned short* __restrict__ wb,
                         const float* __restrict__ bias,
                         float* __restrict__ out) {
    __shared__ unsigned short V[2][32 * VP];   // 2 x 4736 B

    const int tid = threadIdx.x;
    const int p   = tid >> 3;     // position (gather role): 8 lanes share one pos
    const int cg  = tid & 7;      // channel chunk 8ch = 16B
    const int wv  = tid >> 6;     // wave id (MFMA role)
    const int ln  = tid & 63;

    // slab swizzle decode
    const int bx   = blockIdx.x;           // 0..4095
    const int xcd  = bx & 7;
    const int t_   = bx >> 3;              // 0..511
    const int half = t_ >> 8;              // 0..1
    const int slab = xcd + 8 * half;       // 0..15  (slab%8 == xcd)
    const int row  = slab * 32 + ((t_ >> 3) & 31);   // 0..511
    const int b    = row >> 7;
    const int h    = row & 127;
    const int w0   = (t_ & 7) * 32;
    const int w    = w0 + p;

    const uint4* xb4  = (const uint4*)(xn + (size_t)b * HW * 64);
    const float* offb = offset + b * 18 * HW + h * Ww + w;
    unsigned short* vrow0 = &V[0][p * VP + cg * 8];
    unsigned short* vrow1 = &V[1][p * VP + cg * 8];

    const int nt = wv & 1;
    const int mb = (wv >> 1) * 2;
    const unsigned short* wfb = wb + (mb * 16 + (ln & 15)) * Cc + (ln >> 4) * 8;

    floatx4 acc[2];
    acc[0] = (floatx4)0.f; acc[1] = (floatx4)0.f;

    unsigned pf0[16], pf1[16];
    half8 WF0[4], WF1[4];
    Tap tp0, tp1;

    // prologue
    float dy0 = offb[0],        dx0 = offb[HW];
    float dy1 = offb[2 * HW],   dx1 = offb[3 * HW];
    wf_load(wfb, WF0);
    tap_setup(0, h, w, dy0, dx0, cg, tp0);
    tap_load(xb4, tp0, pf0);
    tap_setup(1, h, w, dy1, dx1, cg, tp1);
    tap_load(xb4, tp1, pf1);
    dy0 = offb[4 * HW]; dx0 = offb[5 * HW];
    dy1 = offb[6 * HW]; dx1 = offb[7 * HW];
    tap_store(tp0, pf0, vrow0);
    lds_barrier();

#define PI(K) pipe_iter<K>(xb4, offb, wfb, V[0], V[1], vrow0, vrow1, h, w, cg, nt, ln, \
                           tp0, tp1, pf0, pf1, WF0, WF1, dy0, dx0, dy1, dx1, acc)
    PI(1); PI(2); PI(3); PI(4); PI(5); PI(6); PI(7); PI(8);
#undef PI

    mfma_tap(WF0, V[0], nt, ln, acc);

    float* outp = out + b * COUT * HW + h * Ww;
    const int col = w0 + nt * 16 + (ln & 15);
#pragma unroll
    for (int mi = 0; mi < 2; ++mi)
#pragma unroll
        for (int r = 0; r < 4; ++r) {
            const int o = (mb + mi) * 16 + (ln >> 4) * 4 + r;
            outp[o * HW + col] = acc[mi][r] + bias[o];
        }
}

extern "C" void kernel_launch(void* const* d_in, const int* in_sizes, int n_in,
                              void* d_out, int out_size, void* d_ws, size_t ws_size,
                              hipStream_t stream) {
    const float* x      = (const float*)d_in[0];
    const float* offset = (const float*)d_in[1];
    const float* weight = (const float*)d_in[2];
    const float* bias   = (const float*)d_in[3];
    float* out = (float*)d_out;

    _Float16* xn = (_Float16*)d_ws;                          // 16.8 MiB NHWC fp16
    unsigned short* wb = (unsigned short*)((char*)d_ws + (size_t)Bb * HW * Cc * 2);

    prep<<<dim3(5, Hh, Bb), 256, 0, stream>>>(x, weight, xn, wb);
    dcn_mfma<<<dim3(4096), 256, 0, stream>>>(xn, offset, wb, bias, out);
}